// Round 3
// baseline (1497.621 us; speedup 1.0000x reference)
//
#include <hip/hip_runtime.h>
#include <math.h>

// RNN: T=4096 sequential steps, B=2048, N_HID=32, N_IN=1.
// Round 3 = round 2 with the DPP builtin fixed (ctrl must be an immediate
// -> template parameter). Design: one batch element per wave (2048 waves,
// 8/CU). All 64 lanes redundantly compute h (h = lane&31). h broadcast via
// v_readlane -> 32 SGPRs (NO LDS on the critical chain); the 32-wide dot is
// 32 v_fmac with one SGPR operand each, in 8 accumulator chains
// (bit-identical association to the round-1 kernel that passed).
// Decode sum uses DPP row_shr/row_bcast adds (VALU-only), off critical path.
// x is prefetched 8 steps ahead with a lane-octet vector load (vmcnt, not
// SMEM, so no lgkmcnt(0) drain lands in the chain).

constexpr int T_STEPS = 4096;
constexpr int BATCH   = 2048;
constexpr int NH      = 32;

template <int CTRL>
__device__ __forceinline__ float dpp_sum_add(float v) {
    int m = __builtin_amdgcn_update_dpp(0, __builtin_bit_cast(int, v),
                                        CTRL, 0xf, 0xf, true);
    return v + __builtin_bit_cast(float, m);
}

__global__ __launch_bounds__(64) void rnn_fused_kernel(
    const float* __restrict__ x,      // [T, B]
    const float* __restrict__ hidden, // [B, NH]
    const float* __restrict__ W_ih,   // [NH]
    const float* __restrict__ W_hh,   // [NH, NH]
    const float* __restrict__ b_ih,   // [NH]
    const float* __restrict__ b_hh,   // [NH]
    const float* __restrict__ W_dec,  // [NH]
    const float* __restrict__ b_dec,  // [1]
    float* __restrict__ out)          // [T*B] decoded ++ [B*NH] h_final
{
    const int lane = threadIdx.x;     // 0..63
    const int h    = lane & 31;       // lanes 32-63 mirror 0-31
    const int b    = blockIdx.x;      // one batch element per wave

    // Per-lane constants
    const float wih  = W_ih[h];
    const float cb   = b_ih[h] + b_hh[h];
    const float wdec = W_dec[h];
    const float bdec = b_dec[0];

    // W_hh row h -> 32 VGPRs
    float w[NH];
    #pragma unroll
    for (int k = 0; k < NH; k += 4) {
        float4 v = *(const float4*)(W_hh + h * NH + k);
        w[k] = v.x; w[k+1] = v.y; w[k+2] = v.z; w[k+3] = v.w;
    }

    float hnew = hidden[b * NH + h];

    // x prefetch: lane-octet scheme. xv holds x[t0 + (lane&7)][b] in lane
    // (t0+j) -> consumed via readlane(xv, j). One vector load per 8 steps.
    const float* xb = x + b;
    const int oct = lane & 7;
    float xv = xb[(size_t)oct * BATCH];

    float* outd = out + b;
    constexpr float LOG2E = 1.44269504088896340736f;

    for (int t0 = 0; t0 < T_STEPS; t0 += 8) {
        // prefetch next octet (clamped on tail; values unused past T)
        int tp = t0 + 8 + oct;
        tp = tp < T_STEPS ? tp : (T_STEPS - 1);
        float xn = xb[(size_t)tp * BATCH];

        #pragma unroll
        for (int j = 0; j < 8; ++j) {
            const int t = t0 + j;

            // ---- broadcast h_{t-1} to SGPRs (32 independent readlanes)
            float hs[NH];
            #pragma unroll
            for (int k = 0; k < NH; ++k)
                hs[k] = __builtin_bit_cast(float,
                    __builtin_amdgcn_readlane(__builtin_bit_cast(int, hnew), k));

            // ---- 32-MAC dot: 8 chains, association identical to round 1
            float A0=0.f,A1=0.f,A2=0.f,A3=0.f,B0=0.f,B1=0.f,B2=0.f,B3=0.f;
            #pragma unroll
            for (int i = 0; i < 4; ++i) {
                A0 = fmaf(hs[8*i+0], w[8*i+0], A0);
                B0 = fmaf(hs[8*i+1], w[8*i+1], B0);
                A1 = fmaf(hs[8*i+2], w[8*i+2], A1);
                B1 = fmaf(hs[8*i+3], w[8*i+3], B1);
                A2 = fmaf(hs[8*i+4], w[8*i+4], A2);
                B2 = fmaf(hs[8*i+5], w[8*i+5], B2);
                A3 = fmaf(hs[8*i+6], w[8*i+6], A3);
                B3 = fmaf(hs[8*i+7], w[8*i+7], B3);
            }
            float sA = (A0 + A1) + (A2 + A3);
            float sB = (B0 + B1) + (B2 + B3);
            float dotv = sA + sB;

            // ---- x-projection + relu (x_t via readlane, off chain)
            float xt = __builtin_bit_cast(float,
                __builtin_amdgcn_readlane(__builtin_bit_cast(int, xv), j));
            float xp = fmaf(xt, wih, cb);
            hnew = fmaxf(dotv + xp, 0.0f);

            // ---- fused decode: VALU-only DPP reduce over lanes 0..31,
            // result lands in lane 31 (row_shr within 16-lane rows +
            // row_bcast:15 to cross the 16-lane boundary).
            float d = hnew * wdec;
            d = dpp_sum_add<0x111>(d);  // row_shr:1
            d = dpp_sum_add<0x112>(d);  // row_shr:2
            d = dpp_sum_add<0x114>(d);  // row_shr:4
            d = dpp_sum_add<0x118>(d);  // row_shr:8
            d = dpp_sum_add<0x142>(d);  // row_bcast:15
            float z = d + bdec;
            float e = __builtin_amdgcn_exp2f(-z * LOG2E);
            float sg = __builtin_amdgcn_rcpf(1.0f + e);
            if (lane == 31) outd[(size_t)t * BATCH] = sg;
        }

        xv = xn;
    }

    // ---- final hidden state [B, NH] (lower half only; upper is duplicate)
    if (lane < 32)
        out[(size_t)T_STEPS * BATCH + (size_t)b * NH + h] = hnew;
}

extern "C" void kernel_launch(void* const* d_in, const int* in_sizes, int n_in,
                              void* d_out, int out_size, void* d_ws, size_t ws_size,
                              hipStream_t stream) {
    const float* x      = (const float*)d_in[0];
    const float* hidden = (const float*)d_in[1];
    const float* W_ih   = (const float*)d_in[2];
    const float* W_hh   = (const float*)d_in[3];
    const float* b_ih   = (const float*)d_in[4];
    const float* b_hh   = (const float*)d_in[5];
    const float* W_dec  = (const float*)d_in[6];
    const float* b_dec  = (const float*)d_in[7];
    float* out          = (float*)d_out;

    dim3 grid(BATCH);     // 2048 blocks, 1 wave each (1 batch elem per wave)
    dim3 block(64);
    hipLaunchKernelGGL(rnn_fused_kernel, grid, block, 0, stream,
                       x, hidden, W_ih, W_hh, b_ih, b_hh, W_dec, b_dec, out);
}

// Round 4
// 1154.731 us; speedup vs baseline: 1.2969x; 1.2969x over previous
//
#include <hip/hip_runtime.h>
#include <math.h>

// RNN: T=4096 sequential steps, B=2048, N_HID=32, N_IN=1.
// Round 4: systolic DPP design. 2 batches per wave (lanes 0-31 / 32-63),
// 1024 waves = 1 per SIMD machine-wide. Lane l computes output i = l&31 of
// its batch. The 32-wide recurrent dot splits into:
//   - own 16-row half: 16 x v_fmac with DPP row_ror:r directly on src0
//     (no rotation movs, no dep chain - all rotations read the same reg)
//   - other 16-row half: ONE ds_swizzle (xor 16) per step, then 16 more
//     DPP-rotated fmas. Swizzle latency hides under the own-half fmas.
// W_hh is pre-permuted per lane at init; the DPP row_ror direction is
// PROBED at runtime (wave-uniform) so the permutation can't be backwards.
// Decode uses round-3's verified row_shr/row_bcast:15 DPP reduce (works
// per 32-lane half), sigmoid via exp2/rcp, store from lanes 31/63.

constexpr int T_STEPS = 4096;
constexpr int BATCH   = 2048;
constexpr int NH      = 32;

template <int CTRL>
__device__ __forceinline__ float dpp_f(float v) {
    return __builtin_bit_cast(float, __builtin_amdgcn_update_dpp(
        0, __builtin_bit_cast(int, v), CTRL, 0xf, 0xf, true));
}

__global__ __launch_bounds__(64) void rnn_fused_kernel(
    const float* __restrict__ x,      // [T, B]
    const float* __restrict__ hidden, // [B, NH]
    const float* __restrict__ W_ih,   // [NH]
    const float* __restrict__ W_hh,   // [NH, NH]
    const float* __restrict__ b_ih,   // [NH]
    const float* __restrict__ b_hh,   // [NH]
    const float* __restrict__ W_dec,  // [NH]
    const float* __restrict__ b_dec,  // [1]
    float* __restrict__ out)          // [T*B] decoded ++ [B*NH] h_final
{
    const int lane = threadIdx.x;     // 0..63
    const int i    = lane & 31;       // output index within the batch
    const int half = lane >> 5;       // which batch of the wave's pair
    const int row  = (lane >> 4) & 1; // 16-row within the 32-lane group
    const int p    = lane & 15;       // position within the 16-row
    const int b    = blockIdx.x * 2 + half;

    const float wih  = W_ih[i];
    const float cb   = b_ih[i] + b_hh[i];
    const float wdec = W_dec[i];
    const float bdec = b_dec[0];

    // ---- probe DPP row_ror:1 direction (wave-uniform boolean)
    int rot1 = __builtin_amdgcn_update_dpp(0, p, 0x121, 0xf, 0xf, true);
    const bool minus = (rot1 == ((p - 1) & 15));

    // ---- pre-permuted W_hh: wOwn[r] pairs with row_ror:r of own-row h,
    //      wOth[r] with row_ror:r of the swizzled (other-row) h.
    float wOwn[16], wOth[16];
    #pragma unroll
    for (int r = 0; r < 16; ++r) {
        int q = minus ? ((p - r) & 15) : ((p + r) & 15);
        wOwn[r] = W_hh[i * NH + (row << 4) + q];
        wOth[r] = W_hh[i * NH + ((row ^ 1) << 4) + q];
    }

    float h = hidden[b * NH + i];

    // x prefetch ring, 8 deep (per-lane broadcast loads)
    const float* xb = x + b;
    float xr[8];
    #pragma unroll
    for (int j = 0; j < 8; ++j) xr[j] = xb[(size_t)j * BATCH];

    float* outd = out + b;
    constexpr float NLOG2E = -1.44269504088896340736f;

    for (int t0 = 0; t0 < T_STEPS; t0 += 8) {
        #pragma unroll
        for (int j = 0; j < 8; ++j) {
            const int t = t0 + j;

            // other-row h values (single DS op; lanes 0-31 / 32-63 separate)
            float ho = __builtin_bit_cast(float, __builtin_amdgcn_ds_swizzle(
                __builtin_bit_cast(int, h), 0x401F));

            // own-row half: 16 fmas, DPP rotation on src0, no movs
            float a0 = fmaf(xr[j], wih, cb);
            a0 = fmaf(h, wOwn[0], a0);
            float a1 = 0.0f, c0 = 0.0f, c1 = 0.0f;
#define RS_OWN(R, CTRL, ACC) ACC = fmaf(dpp_f<CTRL>(h), wOwn[R], ACC);
            RS_OWN( 1, 0x121, a1) RS_OWN( 2, 0x122, a0) RS_OWN( 3, 0x123, a1)
            RS_OWN( 4, 0x124, a0) RS_OWN( 5, 0x125, a1) RS_OWN( 6, 0x126, a0)
            RS_OWN( 7, 0x127, a1) RS_OWN( 8, 0x128, a0) RS_OWN( 9, 0x129, a1)
            RS_OWN(10, 0x12A, a0) RS_OWN(11, 0x12B, a1) RS_OWN(12, 0x12C, a0)
            RS_OWN(13, 0x12D, a1) RS_OWN(14, 0x12E, a0) RS_OWN(15, 0x12F, a1)
#undef RS_OWN
            // other-row half (after swizzle result lands)
            c0 = fmaf(ho, wOth[0], c0);
#define RS_OTH(R, CTRL, ACC) ACC = fmaf(dpp_f<CTRL>(ho), wOth[R], ACC);
            RS_OTH( 1, 0x121, c1) RS_OTH( 2, 0x122, c0) RS_OTH( 3, 0x123, c1)
            RS_OTH( 4, 0x124, c0) RS_OTH( 5, 0x125, c1) RS_OTH( 6, 0x126, c0)
            RS_OTH( 7, 0x127, c1) RS_OTH( 8, 0x128, c0) RS_OTH( 9, 0x129, c1)
            RS_OTH(10, 0x12A, c0) RS_OTH(11, 0x12B, c1) RS_OTH(12, 0x12C, c0)
            RS_OTH(13, 0x12D, c1) RS_OTH(14, 0x12E, c0) RS_OTH(15, 0x12F, c1)
#undef RS_OTH

            float dot = (a0 + a1) + (c0 + c1);
            h = fmaxf(dot, 0.0f);

            // ---- fused decode: per-32-lane-half DPP reduce (verified in r3)
            float d = h * wdec;
            d = d + dpp_f<0x111>(d);  // row_shr:1
            d = d + dpp_f<0x112>(d);  // row_shr:2
            d = d + dpp_f<0x114>(d);  // row_shr:4
            d = d + dpp_f<0x118>(d);  // row_shr:8
            d = d + dpp_f<0x142>(d);  // row_bcast:15 (crosses the 16-rows)
            float z = d + bdec;
            float e = __builtin_amdgcn_exp2f(z * NLOG2E);
            float sg = __builtin_amdgcn_rcpf(1.0f + e);
            if (i == 31) outd[(size_t)t * BATCH] = sg;  // lanes 31 and 63

            // prefetch x[t+8]
            int tp = t + 8;
            tp = tp < T_STEPS ? tp : (T_STEPS - 1);
            xr[j] = xb[(size_t)tp * BATCH];
        }
    }

    // ---- final hidden state [B, NH]: 64 contiguous floats per wave
    out[(size_t)T_STEPS * BATCH + (size_t)b * NH + i] = h;
}

extern "C" void kernel_launch(void* const* d_in, const int* in_sizes, int n_in,
                              void* d_out, int out_size, void* d_ws, size_t ws_size,
                              hipStream_t stream) {
    const float* x      = (const float*)d_in[0];
    const float* hidden = (const float*)d_in[1];
    const float* W_ih   = (const float*)d_in[2];
    const float* W_hh   = (const float*)d_in[3];
    const float* b_ih   = (const float*)d_in[4];
    const float* b_hh   = (const float*)d_in[5];
    const float* W_dec  = (const float*)d_in[6];
    const float* b_dec  = (const float*)d_in[7];
    float* out          = (float*)d_out;

    dim3 grid(BATCH / 2);   // 1024 waves: exactly 1 per SIMD machine-wide
    dim3 block(64);
    hipLaunchKernelGGL(rnn_fused_kernel, grid, block, 0, stream,
                       x, hidden, W_ih, W_hh, b_ih, b_hh, W_dec, b_dec, out);
}

// Round 5
// 923.157 us; speedup vs baseline: 1.6223x; 1.2509x over previous
//
#include <hip/hip_runtime.h>
#include <math.h>

// RNN: T=4096 sequential steps, B=2048, N_HID=32, N_IN=1.
// Round 5: k-split design. 1 batch per wave -> 2048 waves = 2 per SIMD
// (latency hiding, fixes r4's 1/SIMD exposure). Lane (i=lane&31,
// kh=lane>>5) computes the k-half [16*kh,16*kh+16) of output i's dot:
//   4x ds_read_b128 (broadcast, conflict-free) + 8x v_pk_fma_f32,
// halves merged by ONE __shfl_xor(32). x-projection folded into the
// accumulator init (kh==1 lanes use zero weight/bias). Decode is the
// r3/r4-verified pure-DPP reduce (VALU only - DS pipe stays lean:
// 4 reads + 1 shfl + 1 write per step). x prefetched 8 steps ahead.

typedef float f32x2 __attribute__((ext_vector_type(2)));
typedef float f32x4 __attribute__((ext_vector_type(4)));

constexpr int T_STEPS = 4096;
constexpr int BATCH   = 2048;
constexpr int NH      = 32;

template <int CTRL>
__device__ __forceinline__ float dpp_f(float v) {
    return __builtin_bit_cast(float, __builtin_amdgcn_update_dpp(
        0, __builtin_bit_cast(int, v), CTRL, 0xf, 0xf, true));
}

__global__ __launch_bounds__(64) void rnn_fused_kernel(
    const float* __restrict__ x,      // [T, B]
    const float* __restrict__ hidden, // [B, NH]
    const float* __restrict__ W_ih,   // [NH]
    const float* __restrict__ W_hh,   // [NH, NH]
    const float* __restrict__ b_ih,   // [NH]
    const float* __restrict__ b_hh,   // [NH]
    const float* __restrict__ W_dec,  // [NH]
    const float* __restrict__ b_dec,  // [1]
    float* __restrict__ out)          // [T*B] decoded ++ [B*NH] h_final
{
    __shared__ __align__(16) float hbuf[NH];

    const int lane = threadIdx.x;     // 0..63
    const int i    = lane & 31;       // output index
    const int kh   = lane >> 5;       // which k-half this lane accumulates
    const int b    = blockIdx.x;      // one batch element per wave

    const float wih  = W_ih[i];
    const float cb   = b_ih[i] + b_hh[i];
    const float wih0 = kh ? 0.0f : wih;   // xp only injected by half 0
    const float cb0  = kh ? 0.0f : cb;
    const float wdec = W_dec[i];
    const float bdec = b_dec[0];

    // My k-half of W_hh row i: 16 weights as 8 packed f32x2
    f32x2 w[8];
    #pragma unroll
    for (int j = 0; j < 4; ++j) {
        f32x4 v = *(const f32x4*)(W_hh + i * NH + kh * 16 + 4 * j);
        w[2*j]   = f32x2{v.x, v.y};
        w[2*j+1] = f32x2{v.z, v.w};
    }

    // init h in LDS (lanes i and i+32 write identical values - benign)
    hbuf[i] = hidden[b * NH + i];

    // x prefetch ring, 8 deep
    const float* xb = x + b;
    float xr[8];
    #pragma unroll
    for (int j = 0; j < 8; ++j) xr[j] = xb[(size_t)j * BATCH];

    float* outd = out + b;
    constexpr float NLOG2E = -1.44269504088896340736f;
    const f32x4* hp = (const f32x4*)hbuf + 4 * kh;  // my 16 h values
    float h = 0.0f;

    for (int t0 = 0; t0 < T_STEPS; t0 += 8) {
        // prefetch next 8 x values (uniform clamped base, stays in-bounds)
        const int tn = (t0 + 8 <= T_STEPS - 8) ? (t0 + 8) : (T_STEPS - 8);
        const float* xnb = xb + (size_t)tn * BATCH;
        float xn[8];
        #pragma unroll
        for (int j = 0; j < 8; ++j) xn[j] = xnb[(size_t)j * BATCH];

        #pragma unroll
        for (int j = 0; j < 8; ++j) {
            // ---- read my 16 h values (broadcast within each half)
            const f32x4 h0 = hp[0], h1 = hp[1], h2 = hp[2], h3 = hp[3];

            // ---- 16 MACs via 8 packed FMAs, 4 accumulator chains.
            //      xp = x*wih + b folded into a0 (half 0 only).
            f32x2 a0 = f32x2{fmaf(xr[j], wih0, cb0), 0.0f};
            f32x2 a1 = f32x2{0.0f, 0.0f};
            f32x2 a2 = f32x2{0.0f, 0.0f};
            f32x2 a3 = f32x2{0.0f, 0.0f};
            a0 = __builtin_elementwise_fma(f32x2{h0.x, h0.y}, w[0], a0);
            a1 = __builtin_elementwise_fma(f32x2{h0.z, h0.w}, w[1], a1);
            a2 = __builtin_elementwise_fma(f32x2{h1.x, h1.y}, w[2], a2);
            a3 = __builtin_elementwise_fma(f32x2{h1.z, h1.w}, w[3], a3);
            a0 = __builtin_elementwise_fma(f32x2{h2.x, h2.y}, w[4], a0);
            a1 = __builtin_elementwise_fma(f32x2{h2.z, h2.w}, w[5], a1);
            a2 = __builtin_elementwise_fma(f32x2{h3.x, h3.y}, w[6], a2);
            a3 = __builtin_elementwise_fma(f32x2{h3.z, h3.w}, w[7], a3);
            f32x2 s = (a0 + a1) + (a2 + a3);
            float part = s.x + s.y;

            // ---- merge the two k-halves across the 32-lane boundary
            float dot = part + __shfl_xor(part, 32, 64);
            h = fmaxf(dot, 0.0f);
            hbuf[i] = h;                    // publish for next step

            // ---- fused decode: pure-VALU DPP reduce (verified r3/r4),
            //      result at lanes 31 (and 63, duplicate)
            float d = h * wdec;
            d = d + dpp_f<0x111>(d);  // row_shr:1
            d = d + dpp_f<0x112>(d);  // row_shr:2
            d = d + dpp_f<0x114>(d);  // row_shr:4
            d = d + dpp_f<0x118>(d);  // row_shr:8
            d = d + dpp_f<0x142>(d);  // row_bcast:15
            float z  = d + bdec;
            float e  = __builtin_amdgcn_exp2f(z * NLOG2E);
            float sg = __builtin_amdgcn_rcpf(1.0f + e);
            if (lane == 31) outd[(size_t)(t0 + j) * BATCH] = sg;

            xr[j] = xn[j];
        }
    }

    // ---- final hidden state [B, NH]
    if (lane < 32)
        out[(size_t)T_STEPS * BATCH + (size_t)b * NH + i] = h;
}

extern "C" void kernel_launch(void* const* d_in, const int* in_sizes, int n_in,
                              void* d_out, int out_size, void* d_ws, size_t ws_size,
                              hipStream_t stream) {
    const float* x      = (const float*)d_in[0];
    const float* hidden = (const float*)d_in[1];
    const float* W_ih   = (const float*)d_in[2];
    const float* W_hh   = (const float*)d_in[3];
    const float* b_ih   = (const float*)d_in[4];
    const float* b_hh   = (const float*)d_in[5];
    const float* W_dec  = (const float*)d_in[6];
    const float* b_dec  = (const float*)d_in[7];
    float* out          = (float*)d_out;

    dim3 grid(BATCH);   // 2048 waves = 2 per SIMD machine-wide
    dim3 block(64);
    hipLaunchKernelGGL(rnn_fused_kernel, grid, block, 0, stream,
                       x, hidden, W_ih, W_hh, b_ih, b_hh, W_dec, b_dec, out);
}